// Round 5
// baseline (1249.489 us; speedup 1.0000x reference)
//
#include <hip/hip_runtime.h>
#include <hip/hip_bf16.h>
#include <cstdint>
#include <cstddef>

#define M_ 4096
#define K_ 7168
#define N_ 18432
#define NT 56     // K-tiles of BK=128
#define ITERS 28  // 2 K-tiles per iteration

typedef __attribute__((ext_vector_type(4))) int i32x4;

#define AS1 __attribute__((address_space(1)))
#define AS3 __attribute__((address_space(3)))

__device__ __forceinline__ void gld_lds16(void* lds, const void* g) {
  __builtin_amdgcn_global_load_lds((const AS1 void*)g, (AS3 void*)lds, 16, 0, 0);
}

// ---------------- prepass 1: per-row dynamic quantization of x ----------------
__global__ __launch_bounds__(256) void quant_x_kernel(const float* __restrict__ x,
                                                      signed char* __restrict__ xq,
                                                      float* __restrict__ sx) {
  const int m = blockIdx.x;
  const float4* row4 = (const float4*)(x + (size_t)m * K_);
  float mx = 0.f;
  for (int i = threadIdx.x; i < K_ / 4; i += 256) {
    float4 v = row4[i];
    mx = fmaxf(mx, fmaxf(fmaxf(fabsf(v.x), fabsf(v.y)), fmaxf(fabsf(v.z), fabsf(v.w))));
  }
#pragma unroll
  for (int d = 1; d < 64; d <<= 1) mx = fmaxf(mx, __shfl_xor(mx, d));
  __shared__ float wred[4];
  if ((threadIdx.x & 63) == 0) wred[threadIdx.x >> 6] = mx;
  __syncthreads();
  mx = fmaxf(fmaxf(wred[0], wred[1]), fmaxf(wred[2], wred[3]));
  const float inv = mx > 0.f ? 127.f / mx : 0.f;
  if (threadIdx.x == 0) sx[m] = mx / 127.f;
  char4* q4 = (char4*)(xq + (size_t)m * K_);
  for (int i = threadIdx.x; i < K_ / 4; i += 256) {
    float4 v = row4[i];
    char4 c;
    c.x = (signed char)__float2int_rn(v.x * inv);
    c.y = (signed char)__float2int_rn(v.y * inv);
    c.z = (signed char)__float2int_rn(v.z * inv);
    c.w = (signed char)__float2int_rn(v.w * inv);
    q4[i] = c;
  }
}

// ---- prepass 2: W int32 [K,N] -> Wt int8 [N,K] (convert + transpose) ----
__global__ __launch_bounds__(256) void transpose_w_kernel(const int* __restrict__ W,
                                                          signed char* __restrict__ Wt) {
  __shared__ __align__(16) signed char t[64][80];
  const int k0 = blockIdx.x * 64;
  const int n0 = blockIdx.y * 64;
  const int r = threadIdx.x >> 4;
  const int c4 = (threadIdx.x & 15) * 4;
#pragma unroll
  for (int rr = 0; rr < 4; ++rr) {
    const int row = rr * 16 + r;
    int4 v = *(const int4*)(W + (size_t)(k0 + row) * N_ + n0 + c4);
    t[c4 + 0][row] = (signed char)v.x;
    t[c4 + 1][row] = (signed char)v.y;
    t[c4 + 2][row] = (signed char)v.z;
    t[c4 + 3][row] = (signed char)v.w;
  }
  __syncthreads();
  const int nr = threadIdx.x >> 2;
  const int cb = (threadIdx.x & 3) * 16;
  int4 o = *(const int4*)&t[nr][cb];
  *(int4*)(Wt + (size_t)(n0 + nr) * K_ + k0 + cb) = o;
}

// ============ main GEMM: 256x256 tile, BK=128, 8-wave ============
// 2 phases per K-tile (32 MFMA each), 1 barrier per phase, counted vmcnt only,
// dual register banks: phase p prefetches phase p+1's fragments during p's MFMA.
// LDS: A [0,65536), B [65536,131072); addr = base + buf*32768 + ks*16384 + row*64 + slot*16
// T2 swizzle: physslot = slot ^ ((row>>1)&3), on gld source (inverse) + ds_read.
__global__ __launch_bounds__(512, 2) void gemm_i8_kernel(const signed char* __restrict__ Aq,
                                                         const signed char* __restrict__ Bt,
                                                         const float* __restrict__ sx,
                                                         const float* __restrict__ scale,
                                                         float* __restrict__ C) {
  __shared__ __align__(16) signed char lds[131072];

  // n-major XCD mapping: each XCD owns 9 n-columns; Wt panel (~1.8MB) stays L2-resident.
  const int bid = blockIdx.x;
  const int xcd = bid & 7;
  const int j = bid >> 3;                     // 0..143
  const int m0 = (j & 15) * 256;              // 16 m-blocks
  const int n0 = (xcd * 9 + (j >> 4)) * 256;  // 72 n-blocks

  const int tid = threadIdx.x;
  const int w = tid >> 6;      // wave 0..7
  const int lane = tid & 63;
  const int wr = w >> 2;       // 0..1 (M)
  const int wc = w & 3;        // 0..3 (N)

  const int fr = lane & 15;
  const int q = lane >> 4;
  const int sl = ((q ^ ((fr >> 1) & 3)) << 4);

  // staging per-lane (inverse-swizzled global source, linear LDS dest)
  const int ls16 = (((lane & 3) ^ ((lane >> 3) & 3)) << 4);
  const int pr0 = w * 16 + (lane >> 2);
  const unsigned offA0 = (unsigned)(m0 + pr0) * K_ + ls16;
  const unsigned offA1 = (unsigned)(m0 + 128 + pr0) * K_ + ls16;
  const unsigned offB0 = (unsigned)(n0 + pr0) * K_ + ls16;
  const unsigned offB1 = (unsigned)(n0 + 128 + pr0) * K_ + ls16;

#define STAGE_A(T, KS) do {                                                        \
    const int tc_ = (T) < NT ? (T) : NT - 1;                                       \
    signed char* d_ = lds + (((T) & 1) * 32768 + (KS) * 16384 + w * 1024);         \
    gld_lds16(d_, Aq + (size_t)offA0 + tc_ * 128 + (KS) * 64);                     \
    gld_lds16(d_ + 8192, Aq + (size_t)offA1 + tc_ * 128 + (KS) * 64);              \
  } while (0)
#define STAGE_B(T, KS) do {                                                        \
    const int tc_ = (T) < NT ? (T) : NT - 1;                                       \
    signed char* d_ = lds + (65536 + ((T) & 1) * 32768 + (KS) * 16384 + w * 1024); \
    gld_lds16(d_, Bt + (size_t)offB0 + tc_ * 128 + (KS) * 64);                     \
    gld_lds16(d_ + 8192, Bt + (size_t)offB1 + tc_ * 128 + (KS) * 64);              \
  } while (0)
// prefetch ALL fragments of (BUF,KS) into bank (FA, FB): 8 A-frags + 4 B-frags
#define LDALL(FA, FB, BUF, KS) do {                                                \
    const signed char* ab = lds + ((BUF) * 32768 + (KS) * 16384);                  \
    const signed char* bb = lds + (65536 + (BUF) * 32768 + (KS) * 16384);          \
    _Pragma("unroll") for (int f_ = 0; f_ < 8; ++f_)                               \
      FA[f_] = *(const i32x4*)(ab + (wr * 128 + f_ * 16 + fr) * 64 + sl);          \
    _Pragma("unroll") for (int n_ = 0; n_ < 4; ++n_)                               \
      FB[n_] = *(const i32x4*)(bb + (wc * 64 + n_ * 16 + fr) * 64 + sl);           \
  } while (0)
#define MFMA32(FA, FB) do {                                                        \
    __builtin_amdgcn_s_setprio(1);                                                 \
    _Pragma("unroll") for (int f_ = 0; f_ < 8; ++f_)                               \
    _Pragma("unroll") for (int n_ = 0; n_ < 4; ++n_)                               \
      acc[f_][n_] = __builtin_amdgcn_mfma_i32_16x16x64_i8(                         \
          FA[f_], FB[n_], acc[f_][n_], 0, 0, 0);                                   \
    __builtin_amdgcn_s_setprio(0);                                                 \
  } while (0)
#define FENCE asm volatile("" ::: "memory")
#define BAR do { FENCE; __builtin_amdgcn_s_barrier(); FENCE; } while (0)
#define VM4 asm volatile("s_waitcnt vmcnt(4)" ::: "memory")
#define VM8 asm volatile("s_waitcnt vmcnt(8)" ::: "memory")
#define SB __builtin_amdgcn_sched_barrier(0)

  i32x4 acc[8][4] = {};
  i32x4 frA0[8], frB0[4], frA1[8], frB1[4];

  // Prologue: stage tiles 0 (buf0) and 1 (buf1) fully (16 gld); wait tile0 (VM8) per wave,
  // barrier (=> ALL waves' tile0 slices landed), then prefetch bank0 <- buf0 ks0.
  STAGE_A(0, 0); STAGE_B(0, 0); STAGE_A(0, 1); STAGE_B(0, 1);
  STAGE_A(1, 0); STAGE_B(1, 0); STAGE_A(1, 1); STAGE_B(1, 1);
  VM8;
  BAR;
  LDALL(frA0, frB0, 0, 0);
  SB;

  for (int it = 0; it < ITERS; ++it) {
    const int u = 2 * it;  // tile u -> buf0, tile u+1 -> buf1
    // P0: MFMA tile u ks0 (bank0) | prefetch bank1 <- buf0 ks1 | stage (u+2):A0,B0
    //     VM4 before BAR: drains tile u+1 fully (guards P1's buf1-ks0 reads)
    LDALL(frA1, frB1, 0, 1);
    SB;
    MFMA32(frA0, frB0);
    SB;
    STAGE_A(u + 2, 0); STAGE_B(u + 2, 0);
    VM4;
    BAR;
    // P1: MFMA tile u ks1 (bank1) | prefetch bank0 <- buf1 ks0 | stage (u+2):A1,B1
    LDALL(frA0, frB0, 1, 0);
    SB;
    MFMA32(frA1, frB1);
    SB;
    STAGE_A(u + 2, 1); STAGE_B(u + 2, 1);
    BAR;
    // P2: MFMA tile u+1 ks0 (bank0) | prefetch bank1 <- buf1 ks1 | stage (u+3):A0,B0
    //     VM4 before BAR: drains tile u+2 fully (guards P3's buf0-ks0 reads)
    LDALL(frA1, frB1, 1, 1);
    SB;
    MFMA32(frA0, frB0);
    SB;
    STAGE_A(u + 3, 0); STAGE_B(u + 3, 0);
    VM4;
    BAR;
    // P3: MFMA tile u+1 ks1 (bank1) | prefetch bank0 <- buf0 ks0 (tile u+2) | stage (u+3):A1,B1
    LDALL(frA0, frB0, 0, 0);
    SB;
    MFMA32(frA1, frB1);
    SB;
    STAGE_A(u + 3, 1); STAGE_B(u + 3, 1);
    BAR;
  }

  // epilogue: y = i32acc * sx[m] * scale[n]; C/D: col=lane&15, row=(lane>>4)*4+reg
  const int mb = m0 + wr * 128;
  const int nb = n0 + wc * 64;
  const int col = lane & 15;
  const int rq = (lane >> 4) * 4;
  float scl[4];
#pragma unroll
  for (int n = 0; n < 4; ++n) scl[n] = scale[nb + n * 16 + col];
#pragma unroll
  for (int m = 0; m < 8; ++m) {
#pragma unroll
    for (int r = 0; r < 4; ++r) {
      const int row = mb + m * 16 + rq + r;
      const float s = sx[row];
      float* out = C + (size_t)row * N_ + nb + col;
#pragma unroll
      for (int n = 0; n < 4; ++n) out[n * 16] = (float)acc[m][n][r] * s * scl[n];
    }
  }
#undef STAGE_A
#undef STAGE_B
#undef LDALL
#undef MFMA32
#undef FENCE
#undef BAR
#undef VM4
#undef VM8
#undef SB
}

// ---------------- fallback (only if ws_size too small): tiled fp32 vector GEMM ----------------
__global__ __launch_bounds__(256) void fb_gemm_kernel(const float* __restrict__ X,
                                                      const int* __restrict__ W,
                                                      const float* __restrict__ scale,
                                                      float* __restrict__ Y) {
  __shared__ float xs[16][65];
  __shared__ float ws_[16][65];
  const int bn = blockIdx.x * 64;
  const int bm = blockIdx.y * 64;
  const int tx = threadIdx.x & 15;
  const int ty = threadIdx.x >> 4;
  float acc[4][4] = {};
  for (int k0 = 0; k0 < K_; k0 += 16) {
    for (int i = threadIdx.x; i < 64 * 16; i += 256) {
      int r = i >> 4, c = i & 15;
      xs[c][r] = X[(size_t)(bm + r) * K_ + k0 + c];
    }
    for (int i = threadIdx.x; i < 16 * 64; i += 256) {
      int r = i >> 6, c = i & 63;
      ws_[r][c] = (float)W[(size_t)(k0 + r) * N_ + bn + c];
    }
    __syncthreads();
#pragma unroll
    for (int kk = 0; kk < 16; ++kk) {
      float a[4], b[4];
#pragma unroll
      for (int i = 0; i < 4; ++i) a[i] = xs[kk][ty * 4 + i];
#pragma unroll
      for (int j = 0; j < 4; ++j) b[j] = ws_[kk][tx * 4 + j];
#pragma unroll
      for (int i = 0; i < 4; ++i)
#pragma unroll
        for (int j = 0; j < 4; ++j) acc[i][j] += a[i] * b[j];
    }
    __syncthreads();
  }
#pragma unroll
  for (int i = 0; i < 4; ++i)
#pragma unroll
    for (int j = 0; j < 4; ++j)
      Y[(size_t)(bm + ty * 4 + i) * N_ + bn + tx * 4 + j] = acc[i][j] * scale[bn + tx * 4 + j];
}

extern "C" void kernel_launch(void* const* d_in, const int* in_sizes, int n_in,
                              void* d_out, int out_size, void* d_ws, size_t ws_size,
                              hipStream_t stream) {
  const float* x = (const float*)d_in[0];
  const int* w = (const int*)d_in[1];  // harness materializes int8 weights as int32
  const float* scale = (const float*)d_in[2];
  float* y = (float*)d_out;

  const size_t xq_bytes = (size_t)M_ * K_;
  const size_t sx_off = xq_bytes;
  const size_t wt_off = sx_off + (size_t)M_ * 4;
  const size_t need = wt_off + (size_t)N_ * K_;  // ~161.5 MB

  if (ws_size >= need) {
    signed char* xq = (signed char*)d_ws;
    float* sx = (float*)((char*)d_ws + sx_off);
    signed char* wt = (signed char*)((char*)d_ws + wt_off);
    hipLaunchKernelGGL(quant_x_kernel, dim3(M_), dim3(256), 0, stream, x, xq, sx);
    hipLaunchKernelGGL(transpose_w_kernel, dim3(K_ / 64, N_ / 64), dim3(256), 0, stream, w, wt);
    hipLaunchKernelGGL(gemm_i8_kernel, dim3((M_ / 256) * (N_ / 256)), dim3(512), 0, stream,
                       xq, wt, sx, scale, y);
  } else {
    hipLaunchKernelGGL(fb_gemm_kernel, dim3(N_ / 64, M_ / 64), dim3(256), 0, stream,
                       x, w, scale, y);
  }
}

// Round 6
// 768.886 us; speedup vs baseline: 1.6251x; 1.6251x over previous
//
#include <hip/hip_runtime.h>
#include <hip/hip_bf16.h>
#include <cstdint>
#include <cstddef>

#define M_ 4096
#define K_ 7168
#define N_ 18432
#define NT 56  // K-tiles of BK=128

typedef __attribute__((ext_vector_type(4))) int i32x4;

#define AS1 __attribute__((address_space(1)))
#define AS3 __attribute__((address_space(3)))

__device__ __forceinline__ void gld_lds16(void* lds, const void* g) {
  __builtin_amdgcn_global_load_lds((const AS1 void*)g, (AS3 void*)lds, 16, 0, 0);
}

// ---------------- prepass 1: per-row dynamic quantization of x ----------------
__global__ __launch_bounds__(256) void quant_x_kernel(const float* __restrict__ x,
                                                      signed char* __restrict__ xq,
                                                      float* __restrict__ sx) {
  const int m = blockIdx.x;
  const float4* row4 = (const float4*)(x + (size_t)m * K_);
  float mx = 0.f;
  for (int i = threadIdx.x; i < K_ / 4; i += 256) {
    float4 v = row4[i];
    mx = fmaxf(mx, fmaxf(fmaxf(fabsf(v.x), fabsf(v.y)), fmaxf(fabsf(v.z), fabsf(v.w))));
  }
#pragma unroll
  for (int d = 1; d < 64; d <<= 1) mx = fmaxf(mx, __shfl_xor(mx, d));
  __shared__ float wred[4];
  if ((threadIdx.x & 63) == 0) wred[threadIdx.x >> 6] = mx;
  __syncthreads();
  mx = fmaxf(fmaxf(wred[0], wred[1]), fmaxf(wred[2], wred[3]));
  const float inv = mx > 0.f ? 127.f / mx : 0.f;
  if (threadIdx.x == 0) sx[m] = mx / 127.f;
  char4* q4 = (char4*)(xq + (size_t)m * K_);
  for (int i = threadIdx.x; i < K_ / 4; i += 256) {
    float4 v = row4[i];
    char4 c;
    c.x = (signed char)__float2int_rn(v.x * inv);
    c.y = (signed char)__float2int_rn(v.y * inv);
    c.z = (signed char)__float2int_rn(v.z * inv);
    c.w = (signed char)__float2int_rn(v.w * inv);
    q4[i] = c;
  }
}

// ---- prepass 2: W int32 [K,N] -> Wt int8 [N,K] (convert + transpose) ----
__global__ __launch_bounds__(256) void transpose_w_kernel(const int* __restrict__ W,
                                                          signed char* __restrict__ Wt) {
  __shared__ __align__(16) signed char t[64][80];
  const int k0 = blockIdx.x * 64;
  const int n0 = blockIdx.y * 64;
  const int r = threadIdx.x >> 4;
  const int c4 = (threadIdx.x & 15) * 4;
#pragma unroll
  for (int rr = 0; rr < 4; ++rr) {
    const int row = rr * 16 + r;
    int4 v = *(const int4*)(W + (size_t)(k0 + row) * N_ + n0 + c4);
    t[c4 + 0][row] = (signed char)v.x;
    t[c4 + 1][row] = (signed char)v.y;
    t[c4 + 2][row] = (signed char)v.z;
    t[c4 + 3][row] = (signed char)v.w;
  }
  __syncthreads();
  const int nr = threadIdx.x >> 2;
  const int cb = (threadIdx.x & 3) * 16;
  int4 o = *(const int4*)&t[nr][cb];
  *(int4*)(Wt + (size_t)(n0 + nr) * K_ + k0 + cb) = o;
}

// ============ main GEMM: 256x256 tile, BK=128, 8-wave, ONE barrier per K-tile ============
// Per K-tile: [24 ds_read + 64 MFMA, compiler-pipelined] -> waitcnt(0,0) (ops ~3000cyc old,
// free) -> s_barrier -> stage tile u+2 into buf[p]. No cross-wave dep inside a tile.
// LDS: A [0,65536), B [65536,131072); addr = base + buf*32768 + ks*16384 + row*64 + slot*16
// T2 swizzle: physslot = slot ^ ((row>>1)&3), on gld source (inverse) + ds_read.
__global__ __launch_bounds__(512, 2) void gemm_i8_kernel(const signed char* __restrict__ Aq,
                                                         const signed char* __restrict__ Bt,
                                                         const float* __restrict__ sx,
                                                         const float* __restrict__ scale,
                                                         float* __restrict__ C) {
  __shared__ __align__(16) signed char lds[131072];

  // n-major XCD mapping: each XCD owns 9 n-columns; Wt panel (~1.8MB) stays L2-resident.
  const int bid = blockIdx.x;
  const int xcd = bid & 7;
  const int j = bid >> 3;                     // 0..143
  const int m0 = (j & 15) * 256;              // 16 m-blocks
  const int n0 = (xcd * 9 + (j >> 4)) * 256;  // 72 n-blocks

  const int tid = threadIdx.x;
  const int w = tid >> 6;      // wave 0..7
  const int lane = tid & 63;
  const int wr = w >> 2;       // 0..1 (M)
  const int wc = w & 3;        // 0..3 (N)

  const int fr = lane & 15;
  const int q = lane >> 4;
  const int sl = ((q ^ ((fr >> 1) & 3)) << 4);

  // staging per-lane (inverse-swizzled global source, linear LDS dest)
  const int ls16 = (((lane & 3) ^ ((lane >> 3) & 3)) << 4);
  const int pr0 = w * 16 + (lane >> 2);
  const unsigned offA0 = (unsigned)(m0 + pr0) * K_ + ls16;
  const unsigned offA1 = (unsigned)(m0 + 128 + pr0) * K_ + ls16;
  const unsigned offB0 = (unsigned)(n0 + pr0) * K_ + ls16;
  const unsigned offB1 = (unsigned)(n0 + 128 + pr0) * K_ + ls16;

#define STAGE_A(T, KS) do {                                                        \
    const int tc_ = (T) < NT ? (T) : NT - 1;                                       \
    signed char* d_ = lds + (((T) & 1) * 32768 + (KS) * 16384 + w * 1024);         \
    gld_lds16(d_, Aq + (size_t)offA0 + tc_ * 128 + (KS) * 64);                     \
    gld_lds16(d_ + 8192, Aq + (size_t)offA1 + tc_ * 128 + (KS) * 64);              \
  } while (0)
#define STAGE_B(T, KS) do {                                                        \
    const int tc_ = (T) < NT ? (T) : NT - 1;                                       \
    signed char* d_ = lds + (65536 + ((T) & 1) * 32768 + (KS) * 16384 + w * 1024); \
    gld_lds16(d_, Bt + (size_t)offB0 + tc_ * 128 + (KS) * 64);                     \
    gld_lds16(d_ + 8192, Bt + (size_t)offB1 + tc_ * 128 + (KS) * 64);              \
  } while (0)
// read all fragments of (BUF,KS): 4 B-frags first, then 8 A-frags (single bank, no pin)
#define LDALL(BUF, KS) do {                                                        \
    const signed char* bb = lds + (65536 + (BUF) * 32768 + (KS) * 16384);          \
    const signed char* ab = lds + ((BUF) * 32768 + (KS) * 16384);                  \
    _Pragma("unroll") for (int n_ = 0; n_ < 4; ++n_)                               \
      fb[n_] = *(const i32x4*)(bb + (wc * 64 + n_ * 16 + fr) * 64 + sl);           \
    _Pragma("unroll") for (int f_ = 0; f_ < 8; ++f_)                               \
      fa[f_] = *(const i32x4*)(ab + (wr * 128 + f_ * 16 + fr) * 64 + sl);          \
  } while (0)
#define MFMA32 do {                                                                \
    __builtin_amdgcn_s_setprio(1);                                                 \
    _Pragma("unroll") for (int f_ = 0; f_ < 8; ++f_)                               \
    _Pragma("unroll") for (int n_ = 0; n_ < 4; ++n_)                               \
      acc[f_][n_] = __builtin_amdgcn_mfma_i32_16x16x64_i8(                         \
          fa[f_], fb[n_], acc[f_][n_], 0, 0, 0);                                   \
    __builtin_amdgcn_s_setprio(0);                                                 \
  } while (0)
#define BARRIER do { asm volatile("" ::: "memory");                                \
                     __builtin_amdgcn_s_barrier();                                 \
                     asm volatile("" ::: "memory"); } while (0)
#define WAIT00 asm volatile("s_waitcnt vmcnt(0) lgkmcnt(0)" ::: "memory")
#define VM8 asm volatile("s_waitcnt vmcnt(8)" ::: "memory")

// one K-tile: compute buf[P] (tile UOFF-2 relative numbering), then restage buf[P]
#define KTILE(P, T_STAGE) do {                                                     \
    LDALL(P, 0);                                                                   \
    MFMA32;                                                                        \
    LDALL(P, 1);                                                                   \
    MFMA32;                                                                        \
    WAIT00;  /* own ds_reads done + previously-staged tile fully landed */         \
    BARRIER; /* all waves done reading buf[P]; next tile visible to all */         \
    STAGE_A(T_STAGE, 0); STAGE_B(T_STAGE, 0);                                      \
    STAGE_A(T_STAGE, 1); STAGE_B(T_STAGE, 1);                                      \
  } while (0)

  i32x4 acc[8][4] = {};
  i32x4 fa[8], fb[4];

  // Prologue: tile0 -> buf0 (8 gld), tile1 -> buf1 (8 gld); wait tile0, barrier.
  STAGE_A(0, 0); STAGE_B(0, 0); STAGE_A(0, 1); STAGE_B(0, 1);
  STAGE_A(1, 0); STAGE_B(1, 0); STAGE_A(1, 1); STAGE_B(1, 1);
  VM8;
  BARRIER;

  for (int it = 0; it < NT / 2; ++it) {
    const int u = 2 * it;
    KTILE(0, u + 2);  // compute tile u   (buf0), restage buf0 with tile u+2
    KTILE(1, u + 3);  // compute tile u+1 (buf1), restage buf1 with tile u+3
  }

  // epilogue: y = i32acc * sx[m] * scale[n]; C/D: col=lane&15, row=(lane>>4)*4+reg
  const int mb = m0 + wr * 128;
  const int nb = n0 + wc * 64;
  const int col = lane & 15;
  const int rq = (lane >> 4) * 4;
  float scl[4];
#pragma unroll
  for (int n = 0; n < 4; ++n) scl[n] = scale[nb + n * 16 + col];
#pragma unroll
  for (int m = 0; m < 8; ++m) {
#pragma unroll
    for (int r = 0; r < 4; ++r) {
      const int row = mb + m * 16 + rq + r;
      const float s = sx[row];
      float* out = C + (size_t)row * N_ + nb + col;
#pragma unroll
      for (int n = 0; n < 4; ++n) out[n * 16] = (float)acc[m][n][r] * s * scl[n];
    }
  }
#undef STAGE_A
#undef STAGE_B
#undef LDALL
#undef MFMA32
#undef BARRIER
#undef WAIT00
#undef VM8
#undef KTILE
}

// ---------------- fallback (only if ws_size too small): tiled fp32 vector GEMM ----------------
__global__ __launch_bounds__(256) void fb_gemm_kernel(const float* __restrict__ X,
                                                      const int* __restrict__ W,
                                                      const float* __restrict__ scale,
                                                      float* __restrict__ Y) {
  __shared__ float xs[16][65];
  __shared__ float ws_[16][65];
  const int bn = blockIdx.x * 64;
  const int bm = blockIdx.y * 64;
  const int tx = threadIdx.x & 15;
  const int ty = threadIdx.x >> 4;
  float acc[4][4] = {};
  for (int k0 = 0; k0 < K_; k0 += 16) {
    for (int i = threadIdx.x; i < 64 * 16; i += 256) {
      int r = i >> 4, c = i & 15;
      xs[c][r] = X[(size_t)(bm + r) * K_ + k0 + c];
    }
    for (int i = threadIdx.x; i < 16 * 64; i += 256) {
      int r = i >> 6, c = i & 63;
      ws_[r][c] = (float)W[(size_t)(k0 + r) * N_ + bn + c];
    }
    __syncthreads();
#pragma unroll
    for (int kk = 0; kk < 16; ++kk) {
      float a[4], b[4];
#pragma unroll
      for (int i = 0; i < 4; ++i) a[i] = xs[kk][ty * 4 + i];
#pragma unroll
      for (int j = 0; j < 4; ++j) b[j] = ws_[kk][tx * 4 + j];
#pragma unroll
      for (int i = 0; i < 4; ++i)
#pragma unroll
        for (int j = 0; j < 4; ++j) acc[i][j] += a[i] * b[j];
    }
    __syncthreads();
  }
#pragma unroll
  for (int i = 0; i < 4; ++i)
#pragma unroll
    for (int j = 0; j < 4; ++j)
      Y[(size_t)(bm + ty * 4 + i) * N_ + bn + tx * 4 + j] = acc[i][j] * scale[bn + tx * 4 + j];
}

extern "C" void kernel_launch(void* const* d_in, const int* in_sizes, int n_in,
                              void* d_out, int out_size, void* d_ws, size_t ws_size,
                              hipStream_t stream) {
  const float* x = (const float*)d_in[0];
  const int* w = (const int*)d_in[1];  // harness materializes int8 weights as int32
  const float* scale = (const float*)d_in[2];
  float* y = (float*)d_out;

  const size_t xq_bytes = (size_t)M_ * K_;
  const size_t sx_off = xq_bytes;
  const size_t wt_off = sx_off + (size_t)M_ * 4;
  const size_t need = wt_off + (size_t)N_ * K_;  // ~161.5 MB

  if (ws_size >= need) {
    signed char* xq = (signed char*)d_ws;
    float* sx = (float*)((char*)d_ws + sx_off);
    signed char* wt = (signed char*)((char*)d_ws + wt_off);
    hipLaunchKernelGGL(quant_x_kernel, dim3(M_), dim3(256), 0, stream, x, xq, sx);
    hipLaunchKernelGGL(transpose_w_kernel, dim3(K_ / 64, N_ / 64), dim3(256), 0, stream, w, wt);
    hipLaunchKernelGGL(gemm_i8_kernel, dim3((M_ / 256) * (N_ / 256)), dim3(512), 0, stream,
                       xq, wt, sx, scale, y);
  } else {
    hipLaunchKernelGGL(fb_gemm_kernel, dim3(N_ / 64, M_ / 64), dim3(256), 0, stream,
                       x, w, scale, y);
  }
}